// Round 1
// baseline (1572.968 us; speedup 1.0000x reference)
//
#include <hip/hip_runtime.h>
#include <cstdint>
#include <cstddef>

#define SB 2048
#define DD 1024
#define NH 16
#define DKH 64

typedef unsigned short ushort_t;
typedef __attribute__((ext_vector_type(8))) short bf16x8;
typedef __attribute__((ext_vector_type(4))) short short4v;
typedef __attribute__((ext_vector_type(4))) float f32x4;

__device__ __forceinline__ unsigned short f2bf(float f) {
  union { float f; unsigned u; } v; v.f = f;
  unsigned u = v.u + (0x7fffu + ((v.u >> 16) & 1u));
  return (unsigned short)(u >> 16);
}

// ---------------- K1: fused QKV projection (Y = X @ W^T + b), bf16 MFMA ----
// z=0: qh [B,H,S,DK]; z=1: kh [B,H,S,DK]; z=2: vhT [B,H,DK,S]
__global__ __launch_bounds__(256) void qkv_proj(
    const float* __restrict__ q, const float* __restrict__ k, const float* __restrict__ v,
    const float* __restrict__ Wq, const float* __restrict__ Wk, const float* __restrict__ Wv,
    const float* __restrict__ bq, const float* __restrict__ bk, const float* __restrict__ bv,
    ushort_t* __restrict__ qh, ushort_t* __restrict__ kh, ushort_t* __restrict__ vhT)
{
  const int z = blockIdx.z;
  const float* X    = (z == 0) ? q  : (z == 1) ? k  : v;
  const float* W    = (z == 0) ? Wq : (z == 1) ? Wk : Wv;
  const float* bias = (z == 0) ? bq : (z == 1) ? bk : bv;
  ushort_t* dst     = (z == 0) ? qh : (z == 1) ? kh : vhT;

  const int tid = threadIdx.x;
  const int wave = tid >> 6, lane = tid & 63;
  const int l15 = lane & 15, quad = lane >> 4;
  const int wr = wave >> 1, wc = wave & 1;
  const int m0 = blockIdx.y * 128, n0 = blockIdx.x * 128;

  // row stride 40 bf16 = 80 B (16B-aligned rows, 2-way bank alias = free)
  __shared__ alignas(16) ushort_t lA[128 * 40];
  __shared__ alignas(16) ushort_t lB[128 * 40];

  f32x4 acc[4][4] = {};

  for (int k0 = 0; k0 < DD; k0 += 32) {
    __syncthreads();
#pragma unroll
    for (int it = 0; it < 4; ++it) {
      int flat = it * 256 + tid;          // 0..1023
      int row = flat >> 3, c4 = flat & 7; // 128 rows x 8 float4
      float4 a = *(const float4*)(X + (size_t)(m0 + row) * DD + k0 + c4 * 4);
      float4 w = *(const float4*)(W + (size_t)(n0 + row) * DD + k0 + c4 * 4);
      short4v av, wv;
      av[0]=(short)f2bf(a.x); av[1]=(short)f2bf(a.y); av[2]=(short)f2bf(a.z); av[3]=(short)f2bf(a.w);
      wv[0]=(short)f2bf(w.x); wv[1]=(short)f2bf(w.y); wv[2]=(short)f2bf(w.z); wv[3]=(short)f2bf(w.w);
      *(short4v*)((char*)lA + row * 80 + c4 * 8) = av;
      *(short4v*)((char*)lB + row * 80 + c4 * 8) = wv;
    }
    __syncthreads();

    bf16x8 af[4], bfr[4];
#pragma unroll
    for (int i = 0; i < 4; ++i)
      af[i] = *(const bf16x8*)((const char*)lA + (wr * 64 + i * 16 + l15) * 80 + quad * 16);
#pragma unroll
    for (int j = 0; j < 4; ++j)
      bfr[j] = *(const bf16x8*)((const char*)lB + (wc * 64 + j * 16 + l15) * 80 + quad * 16);
#pragma unroll
    for (int i = 0; i < 4; ++i)
#pragma unroll
      for (int j = 0; j < 4; ++j)
        acc[i][j] = __builtin_amdgcn_mfma_f32_16x16x32_bf16(af[i], bfr[j], acc[i][j], 0, 0, 0);
  }

#pragma unroll
  for (int j = 0; j < 4; ++j) {
    int n = n0 + wc * 64 + j * 16 + l15;
    float bv_ = bias[n];
    int h = n >> 6, dk = n & 63;
#pragma unroll
    for (int i = 0; i < 4; ++i) {
#pragma unroll
      for (int r = 0; r < 4; ++r) {
        int m = m0 + wr * 64 + i * 16 + quad * 4 + r;   // C layout: row=quad*4+r, col=l15
        int bb = m >> 11, s = m & 2047;
        float val = acc[i][j][r] + bv_;
        size_t off = (z < 2)
          ? ((size_t)((bb * NH + h) * SB + s)) * DKH + dk
          : ((size_t)((bb * NH + h) * DKH + dk)) * SB + s;
        dst[off] = f2bf(val);
      }
    }
  }
}

// ---------------- K2: fused attention (2-pass online softmax + PV) --------
// Changes vs prior verified version:
//  - Q fragments held in registers (lQ removed, -18.4 KB LDS)
//  - K/V tile prefetch: next-tile global loads issued after the post-stage
//    barrier so latency hides under QK-MFMA + softmax (T14 async split)
//  - softmax in exp2 domain (scale = 0.125*log2e folded into logits)
//  - nontemporal stores for the 1 GiB attn output (don't evict K/V in L2)
__global__ __launch_bounds__(256) void attn_kernel(
    const ushort_t* __restrict__ qh, const ushort_t* __restrict__ kh,
    const ushort_t* __restrict__ vhT,
    float* __restrict__ attn, ushort_t* __restrict__ ctx)
{
  const int tid = threadIdx.x;
  const int wave = tid >> 6, lane = tid & 63;
  const int l15 = lane & 15, quad = lane >> 4;
  const int bh = blockIdx.y;            // b*16 + h
  const int b = bh >> 4, h = bh & 15;
  const int q0 = blockIdx.x * 128;

  const ushort_t* Qp = qh  + (size_t)bh * SB * DKH;
  const ushort_t* Kp = kh  + (size_t)bh * SB * DKH;
  const ushort_t* Vp = vhT + (size_t)bh * DKH * SB;
  float* Ap = attn + (size_t)bh * SB * SB + (size_t)q0 * SB;

  __shared__ alignas(16) ushort_t lK[128 * 72];   // stride 144 B
  __shared__ alignas(16) ushort_t lV[64 * 136];   // vhT tile, stride 272 B
  __shared__ alignas(16) ushort_t lP[4][32 * 40]; // per-wave p chunk, stride 80 B

  // Q fragments in registers: each wave only ever reads its own 32 rows.
  // A-frag (16x16x32): row = l15, k-slice = ks*32 + quad*8 .. +8
  bf16x8 aq[2][2];
#pragma unroll
  for (int ks = 0; ks < 2; ++ks)
#pragma unroll
    for (int i = 0; i < 2; ++i)
      aq[ks][i] = *(const bf16x8*)(Qp + (size_t)(q0 + wave * 32 + i * 16 + l15) * DKH
                                   + ks * 32 + quad * 8);

  // logits scaled by (1/sqrt(64)) * log2(e); exp(x) == exp2(x * log2e),
  // applied uniformly so softmax values are exactly the reference ones.
  const float SC = 0.125f * 1.44269504088896f;

  int4 kreg[4], vreg[4];
  auto loadK = [&](int kt) {
#pragma unroll
    for (int it = 0; it < 4; ++it) {
      int flat = it * 256 + tid;
      int row = flat >> 3, c = flat & 7;
      kreg[it] = *(const int4*)(Kp + (size_t)(kt * 128 + row) * DKH + c * 8);
    }
  };
  auto storeK = [&]() {
#pragma unroll
    for (int it = 0; it < 4; ++it) {
      int flat = it * 256 + tid;
      int row = flat >> 3, c = flat & 7;
      *(int4*)((char*)lK + row * 144 + c * 16) = kreg[it];
    }
  };
  auto loadV = [&](int kt) {
#pragma unroll
    for (int it = 0; it < 4; ++it) {
      int flat = it * 256 + tid;
      int row = flat >> 4, c = flat & 15;  // 64 dk-rows x 16 chunks
      vreg[it] = *(const int4*)(Vp + (size_t)row * SB + kt * 128 + c * 8);
    }
  };
  auto storeV = [&]() {
#pragma unroll
    for (int it = 0; it < 4; ++it) {
      int flat = it * 256 + tid;
      int row = flat >> 4, c = flat & 15;
      *(int4*)((char*)lV + row * 272 + c * 16) = vreg[it];
    }
  };

  float mrow[8], lrow[8];
#pragma unroll
  for (int r = 0; r < 8; ++r) { mrow[r] = -1e30f; lrow[r] = 0.f; }

  // ---- pass 1: exact row max + sum ----
  loadK(0);
#pragma unroll 1
  for (int kt = 0; kt < 16; ++kt) {
    storeK();
    __syncthreads();
    if (kt < 15) loadK(kt + 1);   // issued AFTER barrier: vmcnt wait lands at
                                  // next iter's storeK, hidden under compute

    f32x4 sc[2][8] = {};
#pragma unroll
    for (int ks = 0; ks < 2; ++ks) {
      bf16x8 bk8[8];
#pragma unroll
      for (int j = 0; j < 8; ++j)
        bk8[j] = *(const bf16x8*)((const char*)lK + (j * 16 + l15) * 144 + ks * 64 + quad * 16);
#pragma unroll
      for (int i = 0; i < 2; ++i)
#pragma unroll
        for (int j = 0; j < 8; ++j)
          sc[i][j] = __builtin_amdgcn_mfma_f32_16x16x32_bf16(aq[ks][i], bk8[j], sc[i][j], 0, 0, 0);
    }
#pragma unroll
    for (int i = 0; i < 2; ++i)
#pragma unroll
      for (int j = 0; j < 8; ++j)
        sc[i][j] *= SC;

#pragma unroll
    for (int i = 0; i < 2; ++i) {
#pragma unroll
      for (int r = 0; r < 4; ++r) {
        int idx = i * 4 + r;
        float tmax = sc[i][0][r];
#pragma unroll
        for (int j = 1; j < 8; ++j) tmax = fmaxf(tmax, sc[i][j][r]);
        tmax = fmaxf(tmax, __shfl_xor(tmax, 1, 64));
        tmax = fmaxf(tmax, __shfl_xor(tmax, 2, 64));
        tmax = fmaxf(tmax, __shfl_xor(tmax, 4, 64));
        tmax = fmaxf(tmax, __shfl_xor(tmax, 8, 64));
        float mn = fmaxf(mrow[idx], tmax);
        float sum = 0.f;
#pragma unroll
        for (int j = 0; j < 8; ++j) sum += __builtin_amdgcn_exp2f(sc[i][j][r] - mn);
        sum += __shfl_xor(sum, 1, 64);
        sum += __shfl_xor(sum, 2, 64);
        sum += __shfl_xor(sum, 4, 64);
        sum += __shfl_xor(sum, 8, 64);
        lrow[idx] = lrow[idx] * __builtin_amdgcn_exp2f(mrow[idx] - mn) + sum;
        mrow[idx] = mn;
      }
    }
    __syncthreads();
  }

  float rl[8];
#pragma unroll
  for (int r = 0; r < 8; ++r) rl[r] = 1.0f / lrow[r];

  f32x4 oacc[2][4] = {};

  // ---- pass 2: recompute logits, write attn, accumulate PV ----
  loadK(0); loadV(0);
#pragma unroll 1
  for (int kt = 0; kt < 16; ++kt) {
    storeK(); storeV();
    __syncthreads();
    if (kt < 15) { loadK(kt + 1); loadV(kt + 1); }

    f32x4 sc[2][8] = {};
#pragma unroll
    for (int ks = 0; ks < 2; ++ks) {
      bf16x8 bk8[8];
#pragma unroll
      for (int j = 0; j < 8; ++j)
        bk8[j] = *(const bf16x8*)((const char*)lK + (j * 16 + l15) * 144 + ks * 64 + quad * 16);
#pragma unroll
      for (int i = 0; i < 2; ++i)
#pragma unroll
        for (int j = 0; j < 8; ++j)
          sc[i][j] = __builtin_amdgcn_mfma_f32_16x16x32_bf16(aq[ks][i], bk8[j], sc[i][j], 0, 0, 0);
    }
#pragma unroll
    for (int i = 0; i < 2; ++i)
#pragma unroll
      for (int j = 0; j < 8; ++j)
        sc[i][j] *= SC;

#pragma unroll
    for (int i = 0; i < 2; ++i)
#pragma unroll
      for (int r = 0; r < 4; ++r) {
        int idx = i * 4 + r;
        int grow = wave * 32 + i * 16 + quad * 4 + r;
#pragma unroll
        for (int j = 0; j < 8; ++j) {
          float pv = __builtin_amdgcn_exp2f(sc[i][j][r] - mrow[idx]) * rl[idx];
          sc[i][j][r] = pv;
          __builtin_nontemporal_store(pv, Ap + (size_t)grow * SB + kt * 128 + j * 16 + l15);
        }
      }

    // PV in 32-key chunks: C-layout p -> LDS -> A-layout fragments
#pragma unroll
    for (int cch = 0; cch < 4; ++cch) {
#pragma unroll
      for (int i = 0; i < 2; ++i)
#pragma unroll
        for (int jj = 0; jj < 2; ++jj)
#pragma unroll
          for (int r = 0; r < 4; ++r)
            lP[wave][(i * 16 + quad * 4 + r) * 40 + jj * 16 + l15] =
                f2bf(sc[i][cch * 2 + jj][r]);
      __asm__ volatile("s_waitcnt lgkmcnt(0)" ::: "memory");  // wave-private RAW
      bf16x8 pa[2];
#pragma unroll
      for (int i = 0; i < 2; ++i)
        pa[i] = *(const bf16x8*)((const char*)lP[wave] + (i * 16 + l15) * 80 + quad * 16);
#pragma unroll
      for (int jn = 0; jn < 4; ++jn) {
        bf16x8 bv8 = *(const bf16x8*)((const char*)lV + (jn * 16 + l15) * 272 + cch * 64 + quad * 16);
#pragma unroll
        for (int i = 0; i < 2; ++i)
          oacc[i][jn] = __builtin_amdgcn_mfma_f32_16x16x32_bf16(pa[i], bv8, oacc[i][jn], 0, 0, 0);
      }
    }
    __syncthreads();
  }

  // epilogue: ctx in [B,S,D] bf16 for the output projection
#pragma unroll
  for (int i = 0; i < 2; ++i)
#pragma unroll
    for (int jn = 0; jn < 4; ++jn)
#pragma unroll
      for (int r = 0; r < 4; ++r) {
        int qrow = q0 + wave * 32 + i * 16 + quad * 4 + r;
        int dk = jn * 16 + l15;
        ctx[(size_t)(b * SB + qrow) * DD + h * DKH + dk] = f2bf(oacc[i][jn][r]);
      }
}

// ---------------- K3: output projection (fp32 out) -------------------------
__global__ __launch_bounds__(256) void out_proj(
    const ushort_t* __restrict__ ctx, const float* __restrict__ Wo,
    const float* __restrict__ bo, float* __restrict__ out)
{
  const int tid = threadIdx.x;
  const int wave = tid >> 6, lane = tid & 63;
  const int l15 = lane & 15, quad = lane >> 4;
  const int wr = wave >> 1, wc = wave & 1;
  const int m0 = blockIdx.y * 128, n0 = blockIdx.x * 128;

  __shared__ alignas(16) ushort_t lA[128 * 40];
  __shared__ alignas(16) ushort_t lB[128 * 40];

  f32x4 acc[4][4] = {};

  for (int k0 = 0; k0 < DD; k0 += 32) {
    __syncthreads();
#pragma unroll
    for (int it = 0; it < 2; ++it) {     // ctx is already bf16: plain copy
      int flat = it * 256 + tid;         // 0..511
      int row = flat >> 2, c = flat & 3; // 128 rows x 4 chunks of 8 bf16
      *(int4*)((char*)lA + row * 80 + c * 16) =
          *(const int4*)(ctx + (size_t)(m0 + row) * DD + k0 + c * 8);
    }
#pragma unroll
    for (int it = 0; it < 4; ++it) {     // Wo: fp32 -> bf16 convert
      int flat = it * 256 + tid;
      int row = flat >> 3, c4 = flat & 7;
      float4 w = *(const float4*)(Wo + (size_t)(n0 + row) * DD + k0 + c4 * 4);
      short4v wv;
      wv[0]=(short)f2bf(w.x); wv[1]=(short)f2bf(w.y); wv[2]=(short)f2bf(w.z); wv[3]=(short)f2bf(w.w);
      *(short4v*)((char*)lB + row * 80 + c4 * 8) = wv;
    }
    __syncthreads();

    bf16x8 af[4], bfr[4];
#pragma unroll
    for (int i = 0; i < 4; ++i)
      af[i] = *(const bf16x8*)((const char*)lA + (wr * 64 + i * 16 + l15) * 80 + quad * 16);
#pragma unroll
    for (int j = 0; j < 4; ++j)
      bfr[j] = *(const bf16x8*)((const char*)lB + (wc * 64 + j * 16 + l15) * 80 + quad * 16);
#pragma unroll
    for (int i = 0; i < 4; ++i)
#pragma unroll
      for (int j = 0; j < 4; ++j)
        acc[i][j] = __builtin_amdgcn_mfma_f32_16x16x32_bf16(af[i], bfr[j], acc[i][j], 0, 0, 0);
  }

#pragma unroll
  for (int j = 0; j < 4; ++j) {
    int n = n0 + wc * 64 + j * 16 + l15;
    float bv_ = bo[n];
#pragma unroll
    for (int i = 0; i < 4; ++i) {
#pragma unroll
      for (int r = 0; r < 4; ++r) {
        int m = m0 + wr * 64 + i * 16 + quad * 4 + r;
        out[(size_t)m * DD + n] = acc[i][j][r] + bv_;
      }
    }
  }
}

extern "C" void kernel_launch(void* const* d_in, const int* in_sizes, int n_in,
                              void* d_out, int out_size, void* d_ws, size_t ws_size,
                              hipStream_t stream) {
  (void)in_sizes; (void)n_in; (void)out_size; (void)ws_size;
  const float* q  = (const float*)d_in[0];
  const float* k  = (const float*)d_in[1];
  const float* v  = (const float*)d_in[2];
  const float* Wq = (const float*)d_in[3];
  const float* bq = (const float*)d_in[4];
  const float* Wk = (const float*)d_in[5];
  const float* bk = (const float*)d_in[6];
  const float* Wv = (const float*)d_in[7];
  const float* bv = (const float*)d_in[8];
  const float* Wo = (const float*)d_in[9];
  const float* bo = (const float*)d_in[10];

  const size_t NE = (size_t)4 * NH * SB * DKH;  // 8,388,608 elements
  ushort_t* qh  = (ushort_t*)d_ws;              // 16 MB
  ushort_t* kh  = qh  + NE;                     // 16 MB
  ushort_t* vhT = kh  + NE;                     // 16 MB  ([B,H,DK,S])
  ushort_t* ctx = vhT + NE;                     // 16 MB  (total ws: 64 MB)

  float* out  = (float*)d_out;
  float* attn = out + NE;                       // outputs concatenated: out, then attn

  qkv_proj<<<dim3(8, 64, 3), 256, 0, stream>>>(q, k, v, Wq, Wk, Wv, bq, bk, bv, qh, kh, vhT);
  attn_kernel<<<dim3(16, 64), 256, 0, stream>>>(qh, kh, vhT, attn, ctx);
  out_proj<<<dim3(8, 64), 256, 0, stream>>>(ctx, Wo, bo, out);
}